// Round 4
// baseline (545.522 us; speedup 1.0000x reference)
//
#include <hip/hip_runtime.h>
#include <math.h>

// CGBlock fused kernel for MI355X (gfx950) — round 5.
//
// Shapes: B=16, C=256, H=W=128, G=8, Cg=32, K=4.
// out = x + rt*(top_w2 @ yt) + rs*(soft_w2 @ y)     [rt+rs=1 folds the mix]
//
// R5 changes vs R4 (theory: convoy effect — all waves phase-sync, memory
// idles during the ~15us of VALU; overlap requires a software pipeline,
// not occupancy):
//  - Each block processes TILES_=4 tiles (grid 512). Register double
//    buffer vA/vB: loads for tile t+1 are issued BEFORE computing tile t,
//    so the memory pipe always has work (loads t+1 + stores t-1 in
//    flight while VALU runs). The __syncthreads vmcnt drain makes waves
//    wait while memory stays saturated — fine for a BW-bound kernel.
//  - LDS Y double-buffered by tile parity (template arg -> compile-time)
//    so one barrier per tile still suffices: Y[p] rewritten at tile t is
//    protected from tile t-2's readers by tile t-1's barrier.
//  - ~190 VGPR -> 2 waves/SIMD -> 1 block/CU. Occupancy proven not to be
//    the lever (R2/R3 equal); pipelining is.
//  - VALU structure identical to R4 (pk math, med3 top-4, f32x4 LDS).

#define G_ 8
#define K_ 4
#define CG_ 32
#define C_ 256
#define HW_ (128 * 128)
#define TILES_ 4
#define NBLK_ 512

typedef __attribute__((ext_vector_type(2))) float f32x2;
typedef __attribute__((ext_vector_type(4))) float f32x4;

static __device__ __forceinline__ f32x2 pk2(float s) { return f32x2{s, s}; }

static __device__ __forceinline__ f32x2 maxv(f32x2 a, f32x2 b) {
    return __builtin_elementwise_max(a, b);
}

static __device__ __forceinline__ f32x2 fmav(f32x2 a, f32x2 b, f32x2 c) {
    return __builtin_elementwise_fma(a, b, c);
}

// per-component median-of-3 (v_med3_f32)
static __device__ __forceinline__ f32x2 med3v(f32x2 u, f32x2 x, f32x2 y) {
    return f32x2{__builtin_amdgcn_fmed3f(u.x, x.x, y.x),
                 __builtin_amdgcn_fmed3f(u.y, x.y, y.y)};
}

// One tile: optionally prefetch tile+1 into vN, compute on vC, exchange
// through LDS parity buffer PAR, epilogue + store. Fully inlined; all
// array indexing compile-time after unroll.
template <int PAR>
static __device__ __forceinline__ void tile_body(
    const float* __restrict__ x, float* __restrict__ out,
    f32x2 (&vC)[CG_], f32x2 (&vN)[CG_], int tile, bool doLoad, int lane,
    int g, const float* __restrict__ w1g, const float* __restrict__ w2s,
    const float* __restrict__ w2t, float tw0, float tw1, float tw2,
    float tw3, float rs, float rt, f32x4 (&Y)[2][G_][64]) {
    const int b = tile >> 7;
    const int s = ((tile & 127) << 7) | (lane << 1);
    const long base = (long)(b * C_ + g * CG_) * HW_ + s;

    // ---- prefetch next tile into vN (issued before any compute) ----
    if (doLoad) {
        const int nt = tile + 1;
        const int nb = nt >> 7;
        const int ns = ((nt & 127) << 7) | (lane << 1);
        const f32x2* np = (const f32x2*)(x + (long)(nb * C_ + g * CG_) * HW_ + ns);
#pragma unroll
        for (int c = 0; c < CG_; ++c)
            vN[c] = __builtin_nontemporal_load(np + c * (HW_ / 2));
    }

    // ---- softmax branch: max via depth-5 tree, packed accumulate ----
    f32x2 mm[16];
#pragma unroll
    for (int i = 0; i < 16; ++i) mm[i] = maxv(vC[i], vC[i + 16]);
#pragma unroll
    for (int st = 8; st >= 1; st >>= 1) {
#pragma unroll
        for (int i = 0; i < st; ++i) mm[i] = maxv(mm[i], mm[i + st]);
    }
    const f32x2 m = mm[0];

    f32x2 Z = pk2(0.f), acc = pk2(0.f);
#pragma unroll
    for (int c = 0; c < CG_; ++c) {
        const float w1 = w1g[c];                     // wave-uniform -> s_load
        const f32x2 d = vC[c] - m;
        const f32x2 e = f32x2{__expf(d.x), __expf(d.y)};
        Z += e;
        acc = fmav(vC[c] * e, pk2(w1), acc);
    }
    const f32x2 ys = f32x2{acc.x / Z.x, acc.y / Z.y};

    // ---- top-4 branch: max + 3x med3 per element (depth-1) ----
    f32x2 A0 = pk2(-INFINITY), A1 = pk2(-INFINITY);
    f32x2 A2 = pk2(-INFINITY), A3 = pk2(-INFINITY);
#pragma unroll
    for (int c = 0; c < CG_; ++c) {
        const f32x2 u = vC[c];
        const f32x2 n0 = maxv(A0, u);
        const f32x2 n1 = med3v(u, A0, A1);
        const f32x2 n2 = med3v(u, A1, A2);
        const f32x2 n3 = med3v(u, A2, A3);
        A0 = n0; A1 = n1; A2 = n2; A3 = n3;
    }
    f32x2 yt = A3 * pk2(tw3);
    yt = fmav(A2, pk2(tw2), yt);
    yt = fmav(A1, pk2(tw1), yt);
    yt = fmav(A0, pk2(tw0), yt);

    // ---- exchange per-position group features through LDS ----
    const f32x2 yss = ys * pk2(rs);
    const f32x2 ytt = yt * pk2(rt);
    Y[PAR][g][lane] = f32x4{yss.x, yss.y, ytt.x, ytt.y};
    __syncthreads();

    f32x4 yv[G_];
#pragma unroll
    for (int gg = 0; gg < G_; ++gg) yv[gg] = Y[PAR][gg][lane];  // ds_read_b128

    // ---- epilogue: out[c] = x[c] + sum_gg (w2s*ys + w2t*yt), pk FMAs ----
    f32x2* op = (f32x2*)(out + base);
#pragma unroll
    for (int c = 0; c < CG_; ++c) {
        f32x2 o = vC[c];
#pragma unroll
        for (int gg = 0; gg < G_; ++gg) {
            const float cs = w2s[c * G_ + gg];       // wave-uniform -> s_load
            const float ct = w2t[c * G_ + gg];
            o = fmav(pk2(cs), f32x2{yv[gg].x, yv[gg].y}, o);   // v_pk_fma_f32
            o = fmav(pk2(ct), f32x2{yv[gg].z, yv[gg].w}, o);   // v_pk_fma_f32
        }
        __builtin_nontemporal_store(o, op + c * (HW_ / 2));
    }
}

__launch_bounds__(512, 2)
__global__ void cgblock_kernel(const float* __restrict__ x,
                               const float* __restrict__ soft_w1,  // [G, Cg]
                               const float* __restrict__ soft_w2,  // [C, G]
                               const float* __restrict__ top_w1,   // [G, K]
                               const float* __restrict__ top_w2,   // [C, G]
                               const float* __restrict__ r,        // [2]
                               float* __restrict__ out) {
    __shared__ f32x4 Y[2][G_][64];                   // 16 KiB, parity dbuf

    const int lane = threadIdx.x & 63;
    const int g = __builtin_amdgcn_readfirstlane(threadIdx.x >> 6);
    const int tile0 = blockIdx.x * TILES_;

    // branch mixing weights: softmax(r) -> rt (top), rs (soft)
    const float e0 = __expf(r[0]);
    const float e1 = __expf(r[1]);
    const float rt = e0 / (e0 + e1);
    const float rs = e1 / (e0 + e1);

    const float* w1g = soft_w1 + g * CG_;
    const float* w2s = soft_w2 + g * CG_ * G_;
    const float* w2t = top_w2 + g * CG_ * G_;
    const float tw0 = top_w1[g * K_ + 0], tw1 = top_w1[g * K_ + 1];
    const float tw2 = top_w1[g * K_ + 2], tw3 = top_w1[g * K_ + 3];

    f32x2 vA[CG_], vB[CG_];

    // ---- prologue: load tile0 -> vA ----
    {
        const int b = tile0 >> 7;
        const int s = ((tile0 & 127) << 7) | (lane << 1);
        const f32x2* xp = (const f32x2*)(x + (long)(b * C_ + g * CG_) * HW_ + s);
#pragma unroll
        for (int c = 0; c < CG_; ++c)
            vA[c] = __builtin_nontemporal_load(xp + c * (HW_ / 2));
    }

    // ---- pipelined tile loop (2-step, explicit ping-pong buffers) ----
#pragma unroll 1
    for (int t = 0; t < TILES_; t += 2) {
        tile_body<0>(x, out, vA, vB, tile0 + t, true, lane, g, w1g, w2s,
                     w2t, tw0, tw1, tw2, tw3, rs, rt, Y);
        tile_body<1>(x, out, vB, vA, tile0 + t + 1, (t + 2 < TILES_), lane,
                     g, w1g, w2s, w2t, tw0, tw1, tw2, tw3, rs, rt, Y);
    }
}

extern "C" void kernel_launch(void* const* d_in, const int* in_sizes, int n_in,
                              void* d_out, int out_size, void* d_ws, size_t ws_size,
                              hipStream_t stream) {
    const float* x       = (const float*)d_in[0];
    const float* soft_w1 = (const float*)d_in[1];
    const float* soft_w2 = (const float*)d_in[2];
    const float* top_w1  = (const float*)d_in[3];
    const float* top_w2  = (const float*)d_in[4];
    const float* r       = (const float*)d_in[5];
    float* out = (float*)d_out;

    // grid: 512 blocks x 4 tiles = 2048 tiles (16 images x 128 chunks)
    cgblock_kernel<<<dim3(NBLK_), dim3(512), 0, stream>>>(
        x, soft_w1, soft_w2, top_w1, top_w2, r, out);
}